// Round 1
// baseline (2214.491 us; speedup 1.0000x reference)
//
#include <hip/hip_runtime.h>

#define N_NODES 100000
#define N_EDGES 1600000
constexpr int BLK = 256;

// ---------- edge dtype detection (int32 vs int64-lowword) ----------
__global__ void detect_idx64(const unsigned int* __restrict__ e, int* __restrict__ flag) {
    if (blockIdx.x == 0 && threadIdx.x == 0) {
        int is64 = 1;
        for (int i = 0; i < 64; ++i) if (e[2 * i + 1] != 0u) { is64 = 0; break; }
        *flag = is64;   // int64 values < 2^17 have zero high words; int32 data won't
    }
}

__global__ void convert_edges(const int* __restrict__ e, int* __restrict__ out,
                              int total, const int* __restrict__ flag) {
    const int f = *flag;
    int i = blockIdx.x * BLK + threadIdx.x;
    if (i < total) out[i] = f ? e[2 * i] : e[i];
}

__global__ void degree_kernel(const int* __restrict__ dst, int* __restrict__ cnt) {
    int i = blockIdx.x * BLK + threadIdx.x;
    if (i < N_EDGES) atomicAdd(&cnt[dst[i]], 1);
}

// ---------- helpers ----------
__device__ __forceinline__ void fma_step(float4& acc, float xs, float4 w) {
    acc.x = fmaf(xs, w.x, acc.x);
    acc.y = fmaf(xs, w.y, acc.y);
    acc.z = fmaf(xs, w.z, acc.z);
    acc.w = fmaf(xs, w.w, acc.w);
}

// ---------- Y[n,C] = X[n,K] @ W[K,C] + b ----------
// W staged in LDS; thread = (node-slot, channel-quad); x read as broadcast float4.
template<int K, int C>
__global__ void gemm_bias(const float* __restrict__ X, const float* __restrict__ W,
                          const float* __restrict__ bias, float* __restrict__ Y, int n) {
    constexpr int CQ = C / 4;        // channel quads
    constexpr int NPB = BLK / CQ;    // nodes per block
    __shared__ float4 Ws[K * CQ];
    for (int i = threadIdx.x; i < K * CQ; i += BLK)
        Ws[i] = reinterpret_cast<const float4*>(W)[i];
    __syncthreads();
    const int cq = threadIdx.x % CQ;
    const int ns = threadIdx.x / CQ;
    const float4 bv = reinterpret_cast<const float4*>(bias)[cq];
    const int ntiles = (n + NPB - 1) / NPB;
    for (int tile = blockIdx.x; tile < ntiles; tile += gridDim.x) {
        const int node = tile * NPB + ns;
        if (node >= n) continue;
        const float4* xr = reinterpret_cast<const float4*>(X + (size_t)node * K);
        float4 acc = bv;
#pragma unroll 4
        for (int k4 = 0; k4 < K / 4; ++k4) {
            float4 xv = xr[k4];
            fma_step(acc, xv.x, Ws[(4 * k4 + 0) * CQ + cq]);
            fma_step(acc, xv.y, Ws[(4 * k4 + 1) * CQ + cq]);
            fma_step(acc, xv.z, Ws[(4 * k4 + 2) * CQ + cq]);
            fma_step(acc, xv.w, Ws[(4 * k4 + 3) * CQ + cq]);
        }
        reinterpret_cast<float4*>(Y + (size_t)node * C)[cq] = acc;
    }
}

// ---------- scatter: AGG[dst] += H[src]  (float atomics) ----------
template<int C>
__global__ void scatter_kernel(const int* __restrict__ src, const int* __restrict__ dst,
                               const float* __restrict__ H, float* __restrict__ AGG) {
    constexpr int Q = C / 4;
    constexpr int QSH = (Q == 16) ? 4 : 3;
    const int total = N_EDGES * Q;
    const int stride = gridDim.x * BLK;
    for (int i = blockIdx.x * BLK + threadIdx.x; i < total; i += stride) {
        const int e = i >> QSH;
        const int q = i & (Q - 1);
        const int s = src[e];
        const int d = dst[e];
        float4 v = reinterpret_cast<const float4*>(H + (size_t)s * C)[q];
        float* a = AGG + (size_t)d * C + 4 * q;
        atomicAdd(a + 0, v.x);
        atomicAdd(a + 1, v.y);
        atomicAdd(a + 2, v.z);
        atomicAdd(a + 3, v.w);
    }
}

// ---------- update: Y = relu( concat(P, (A+P)/(cnt+1)) @ W + b ) ----------
template<int KH, int C>
__global__ void update_relu(const float* __restrict__ P, const float* __restrict__ A,
                            const int* __restrict__ cnt,
                            const float* __restrict__ W, const float* __restrict__ bias,
                            float* __restrict__ Y, int n) {
    constexpr int CQ = C / 4;
    constexpr int NPB = BLK / CQ;
    constexpr int K = 2 * KH;
    __shared__ float4 Ws[K * CQ];
    for (int i = threadIdx.x; i < K * CQ; i += BLK)
        Ws[i] = reinterpret_cast<const float4*>(W)[i];
    __syncthreads();
    const int cq = threadIdx.x % CQ;
    const int ns = threadIdx.x / CQ;
    const float4 bv = reinterpret_cast<const float4*>(bias)[cq];
    const int ntiles = (n + NPB - 1) / NPB;
    for (int tile = blockIdx.x; tile < ntiles; tile += gridDim.x) {
        const int node = tile * NPB + ns;
        if (node >= n) continue;
        const float inv = 1.0f / (float)(cnt[node] + 1);   // +1 self loop
        const float4* pr = reinterpret_cast<const float4*>(P + (size_t)node * KH);
        const float4* ar = reinterpret_cast<const float4*>(A + (size_t)node * KH);
        float4 acc = bv;
#pragma unroll 4
        for (int k4 = 0; k4 < KH / 4; ++k4) {
            float4 pv = pr[k4];
            float4 av = ar[k4];
            fma_step(acc, pv.x, Ws[(4 * k4 + 0) * CQ + cq]);
            fma_step(acc, pv.y, Ws[(4 * k4 + 1) * CQ + cq]);
            fma_step(acc, pv.z, Ws[(4 * k4 + 2) * CQ + cq]);
            fma_step(acc, pv.w, Ws[(4 * k4 + 3) * CQ + cq]);
            fma_step(acc, (av.x + pv.x) * inv, Ws[(KH + 4 * k4 + 0) * CQ + cq]);
            fma_step(acc, (av.y + pv.y) * inv, Ws[(KH + 4 * k4 + 1) * CQ + cq]);
            fma_step(acc, (av.z + pv.z) * inv, Ws[(KH + 4 * k4 + 2) * CQ + cq]);
            fma_step(acc, (av.w + pv.w) * inv, Ws[(KH + 4 * k4 + 3) * CQ + cq]);
        }
        acc.x = fmaxf(acc.x, 0.0f);
        acc.y = fmaxf(acc.y, 0.0f);
        acc.z = fmaxf(acc.z, 0.0f);
        acc.w = fmaxf(acc.w, 0.0f);
        reinterpret_cast<float4*>(Y + (size_t)node * C)[cq] = acc;
    }
}

// ---------- conv2 update fused with final 32->1 linear ----------
__global__ void update2_final(const float* __restrict__ P, const float* __restrict__ A,
                              const int* __restrict__ cnt,
                              const float* __restrict__ W, const float* __restrict__ bias,
                              const float* __restrict__ Wl, const float* __restrict__ bl,
                              float* __restrict__ out, int n) {
    __shared__ float Ws[64 * 32];   // 8 KB
    for (int i = threadIdx.x; i < 64 * 32; i += BLK) Ws[i] = W[i];
    __syncthreads();
    const int c = threadIdx.x & 31;
    const int ns = threadIdx.x >> 5;     // 0..7 node slots
    const float wl = Wl[c];
    const float bc = bias[c];
    const float blv = bl[0];
    const int ntiles = (n + 7) / 8;
    for (int tile = blockIdx.x; tile < ntiles; tile += gridDim.x) {
        const int node = tile * 8 + ns;
        float v = 0.0f;
        if (node < n) {
            const float inv = 1.0f / (float)(cnt[node] + 1);
            const float4* pr = reinterpret_cast<const float4*>(P + (size_t)node * 32);
            const float4* ar = reinterpret_cast<const float4*>(A + (size_t)node * 32);
            float acc = bc;
#pragma unroll
            for (int k4 = 0; k4 < 8; ++k4) {
                float4 pv = pr[k4];
                float4 av = ar[k4];
                const int k = 4 * k4;
                acc = fmaf(pv.x, Ws[(k + 0) * 32 + c], acc);
                acc = fmaf(pv.y, Ws[(k + 1) * 32 + c], acc);
                acc = fmaf(pv.z, Ws[(k + 2) * 32 + c], acc);
                acc = fmaf(pv.w, Ws[(k + 3) * 32 + c], acc);
                acc = fmaf((av.x + pv.x) * inv, Ws[(32 + k + 0) * 32 + c], acc);
                acc = fmaf((av.y + pv.y) * inv, Ws[(32 + k + 1) * 32 + c], acc);
                acc = fmaf((av.z + pv.z) * inv, Ws[(32 + k + 2) * 32 + c], acc);
                acc = fmaf((av.w + pv.w) * inv, Ws[(32 + k + 3) * 32 + c], acc);
            }
            v = fmaxf(acc, 0.0f) * wl;
        }
#pragma unroll
        for (int off = 16; off >= 1; off >>= 1) v += __shfl_xor(v, off, 64);
        if (c == 0 && node < n) out[node] = v + blv;
    }
}

extern "C" void kernel_launch(void* const* d_in, const int* in_sizes, int n_in,
                              void* d_out, int out_size, void* d_ws, size_t ws_size,
                              hipStream_t stream) {
    const float* x    = (const float*)d_in[0];
    const int*   eraw = (const int*)d_in[1];
    const float* W2_1 = (const float*)d_in[2];
    const float* b2_1 = (const float*)d_in[3];
    const float* W1_1 = (const float*)d_in[4];
    const float* b1_1 = (const float*)d_in[5];
    const float* W2_2 = (const float*)d_in[6];
    const float* b2_2 = (const float*)d_in[7];
    const float* W1_2 = (const float*)d_in[8];
    const float* b1_2 = (const float*)d_in[9];
    const float* Wl   = (const float*)d_in[10];
    const float* bl   = (const float*)d_in[11];
    float* out = (float*)d_out;

    // workspace layout (~90.6 MB)
    char* ws = (char*)d_ws;
    int* flag = (int*)ws;
    int* e32  = (int*)(ws + 256);
    size_t off = 256 + sizeof(int) * 2 * (size_t)N_EDGES;
    int* cnt = (int*)(ws + off);
    off += sizeof(int) * (size_t)N_NODES;
    off = (off + 255) & ~(size_t)255;
    float* bufA = (float*)(ws + off); off += sizeof(float) * (size_t)N_NODES * 64;
    float* bufB = (float*)(ws + off); off += sizeof(float) * (size_t)N_NODES * 64;
    float* bufC = (float*)(ws + off); off += sizeof(float) * (size_t)N_NODES * 64;

    const int* src = e32;
    const int* dst = e32 + N_EDGES;

    hipMemsetAsync(cnt, 0, sizeof(int) * (size_t)N_NODES, stream);
    hipMemsetAsync(bufB, 0, sizeof(float) * (size_t)N_NODES * 64, stream);

    detect_idx64<<<1, 64, 0, stream>>>((const unsigned int*)eraw, flag);
    convert_edges<<<(2 * N_EDGES + BLK - 1) / BLK, BLK, 0, stream>>>(eraw, e32, 2 * N_EDGES, flag);
    degree_kernel<<<(N_EDGES + BLK - 1) / BLK, BLK, 0, stream>>>(dst, cnt);

    // conv1
    gemm_bias<128, 64><<<2048, BLK, 0, stream>>>(x, W2_1, b2_1, bufA, N_NODES);
    scatter_kernel<64><<<8192, BLK, 0, stream>>>(src, dst, bufA, bufB);
    update_relu<64, 64><<<2048, BLK, 0, stream>>>(bufA, bufB, cnt, W1_1, b1_1, bufC, N_NODES);

    // conv2 (h2pre reuses bufA; agg2 reuses bufB)
    gemm_bias<64, 32><<<2048, BLK, 0, stream>>>(bufC, W2_2, b2_2, bufA, N_NODES);
    hipMemsetAsync(bufB, 0, sizeof(float) * (size_t)N_NODES * 32, stream);
    scatter_kernel<32><<<8192, BLK, 0, stream>>>(src, dst, bufA, bufB);

    // conv2 update + final linear fused
    update2_final<<<4096, BLK, 0, stream>>>(bufA, bufB, cnt, W1_2, b1_2, Wl, bl, out, N_NODES);
}

// Round 3
// 461.410 us; speedup vs baseline: 4.7994x; 4.7994x over previous
//
#include <hip/hip_runtime.h>

#define N_NODES 100000
#define N_EDGES 1600000
constexpr int BLK = 256;
constexpr int NB_SCAN = (N_NODES + 255) / 256;   // 391

// ---------- edge dtype detection (int32 vs int64-lowword) ----------
__global__ void detect_idx64(const unsigned int* __restrict__ e, int* __restrict__ flag) {
    if (blockIdx.x == 0 && threadIdx.x == 0) {
        int is64 = 1;
        for (int i = 0; i < 64; ++i) if (e[2 * i + 1] != 0u) { is64 = 0; break; }
        *flag = is64;
    }
}

__global__ void convert_edges(const int* __restrict__ e, int* __restrict__ out,
                              int total, const int* __restrict__ flag) {
    const int f = *flag;
    int i = blockIdx.x * BLK + threadIdx.x;
    if (i < total) out[i] = f ? e[2 * i] : e[i];
}

__global__ void degree_kernel(const int* __restrict__ dst, int* __restrict__ cnt) {
    int i = blockIdx.x * BLK + threadIdx.x;
    if (i < N_EDGES) atomicAdd(&cnt[dst[i]], 1);
}

// ---------- 3-kernel exclusive scan over cnt -> rowptr ----------
__global__ void scan_block(const int* __restrict__ cnt, int* __restrict__ rowptr,
                           int* __restrict__ bsum, int n) {
    __shared__ int tmp[256];
    const int i = blockIdx.x * 256 + threadIdx.x;
    const int v = (i < n) ? cnt[i] : 0;
    tmp[threadIdx.x] = v;
    __syncthreads();
    for (int off = 1; off < 256; off <<= 1) {
        int t = (threadIdx.x >= off) ? tmp[threadIdx.x - off] : 0;
        __syncthreads();
        tmp[threadIdx.x] += t;
        __syncthreads();
    }
    if (i < n) rowptr[i] = tmp[threadIdx.x] - v;     // exclusive
    if (threadIdx.x == 255) bsum[blockIdx.x] = tmp[255];
}

__global__ void scan_bsum(int* __restrict__ bsum, int nb) {
    __shared__ int tmp[256];
    __shared__ int carry;
    if (threadIdx.x == 0) carry = 0;
    __syncthreads();
    for (int base = 0; base < nb; base += 256) {
        const int i = base + threadIdx.x;
        const int v = (i < nb) ? bsum[i] : 0;
        tmp[threadIdx.x] = v;
        __syncthreads();
        for (int off = 1; off < 256; off <<= 1) {
            int t = (threadIdx.x >= off) ? tmp[threadIdx.x - off] : 0;
            __syncthreads();
            tmp[threadIdx.x] += t;
            __syncthreads();
        }
        const int c = carry;
        if (i < nb) bsum[i] = c + tmp[threadIdx.x] - v;   // exclusive
        __syncthreads();
        if (threadIdx.x == 255) carry = c + tmp[255];
        __syncthreads();
    }
}

__global__ void scan_add(int* __restrict__ rowptr, int* __restrict__ cursor,
                         const int* __restrict__ bsum, int n) {
    const int i = blockIdx.x * 256 + threadIdx.x;
    if (i < n) {
        const int v = rowptr[i] + bsum[blockIdx.x];
        rowptr[i] = v;
        cursor[i] = v;
    }
}

__global__ void fill_csr(const int* __restrict__ src, const int* __restrict__ dst,
                         int* __restrict__ cursor, int* __restrict__ adj) {
    const int e = blockIdx.x * BLK + threadIdx.x;
    if (e < N_EDGES) {
        const int pos = atomicAdd(&cursor[dst[e]], 1);
        adj[pos] = src[e];
    }
}

// ---------- helpers ----------
__device__ __forceinline__ void fma_step(float4& acc, float xs, float4 w) {
    acc.x = fmaf(xs, w.x, acc.x);
    acc.y = fmaf(xs, w.y, acc.y);
    acc.z = fmaf(xs, w.z, acc.z);
    acc.w = fmaf(xs, w.w, acc.w);
}

__device__ __forceinline__ void add4(float4& a, float4 v) {
    a.x += v.x; a.y += v.y; a.z += v.z; a.w += v.w;
}

// ---------- Y[n,C] = X[n,K] @ W[K,C] + b ----------
template<int K, int C>
__global__ void gemm_bias(const float* __restrict__ X, const float* __restrict__ W,
                          const float* __restrict__ bias, float* __restrict__ Y, int n) {
    constexpr int CQ = C / 4;
    constexpr int NPB = BLK / CQ;
    __shared__ float4 Ws[K * CQ];
    for (int i = threadIdx.x; i < K * CQ; i += BLK)
        Ws[i] = reinterpret_cast<const float4*>(W)[i];
    __syncthreads();
    const int cq = threadIdx.x % CQ;
    const int ns = threadIdx.x / CQ;
    const float4 bv = reinterpret_cast<const float4*>(bias)[cq];
    const int ntiles = (n + NPB - 1) / NPB;
    for (int tile = blockIdx.x; tile < ntiles; tile += gridDim.x) {
        const int node = tile * NPB + ns;
        if (node >= n) continue;
        const float4* xr = reinterpret_cast<const float4*>(X + (size_t)node * K);
        float4 acc = bv;
#pragma unroll 4
        for (int k4 = 0; k4 < K / 4; ++k4) {
            float4 xv = xr[k4];
            fma_step(acc, xv.x, Ws[(4 * k4 + 0) * CQ + cq]);
            fma_step(acc, xv.y, Ws[(4 * k4 + 1) * CQ + cq]);
            fma_step(acc, xv.z, Ws[(4 * k4 + 2) * CQ + cq]);
            fma_step(acc, xv.w, Ws[(4 * k4 + 3) * CQ + cq]);
        }
        reinterpret_cast<float4*>(Y + (size_t)node * C)[cq] = acc;
    }
}

// ---------- fused gather-aggregate + update: Y = relu(concat(P, agg) @ W + b) ----------
// agg = (sum_{j in N(i)} P[j] + P[i]) / (deg+1)
template<int KH, int C>
__global__ void update_gather(const float* __restrict__ P,
                              const int* __restrict__ rowptr, const int* __restrict__ cnt,
                              const int* __restrict__ adj,
                              const float* __restrict__ W, const float* __restrict__ bias,
                              float* __restrict__ Y, int n) {
    constexpr int CQ = C / 4;          // also = KH/4 here (KH == C)
    constexpr int NPB = BLK / CQ;
    constexpr int K = 2 * KH;
    __shared__ float4 Ws[K * CQ];
    __shared__ float4 Ag[NPB][CQ];
    for (int i = threadIdx.x; i < K * CQ; i += BLK)
        Ws[i] = reinterpret_cast<const float4*>(W)[i];
    __syncthreads();
    const int cq = threadIdx.x % CQ;
    const int ns = threadIdx.x / CQ;
    const float4 bv = reinterpret_cast<const float4*>(bias)[cq];
    const int ntiles = (n + NPB - 1) / NPB;   // divides evenly for our sizes
    for (int tile = blockIdx.x; tile < ntiles; tile += gridDim.x) {
        const int node = tile * NPB + ns;
        const int start = rowptr[node];
        const int deg = cnt[node];
        const float inv = 1.0f / (float)(deg + 1);
        const float4* pr = reinterpret_cast<const float4*>(P + (size_t)node * KH);

        // gather-sum neighbors (quad cq of each neighbor row)
        float4 agg = {0.f, 0.f, 0.f, 0.f};
        int j = 0;
        for (; j + 1 < deg; j += 2) {
            const int s0 = adj[start + j];
            const int s1 = adj[start + j + 1];
            float4 v0 = reinterpret_cast<const float4*>(P + (size_t)s0 * KH)[cq];
            float4 v1 = reinterpret_cast<const float4*>(P + (size_t)s1 * KH)[cq];
            add4(agg, v0);
            add4(agg, v1);
        }
        if (j < deg) {
            const int s0 = adj[start + j];
            add4(agg, reinterpret_cast<const float4*>(P + (size_t)s0 * KH)[cq]);
        }

        float4 acc = bv;
#pragma unroll 4
        for (int k4 = 0; k4 < KH / 4; ++k4) {
            float4 pv = pr[k4];
            fma_step(acc, pv.x, Ws[(4 * k4 + 0) * CQ + cq]);
            fma_step(acc, pv.y, Ws[(4 * k4 + 1) * CQ + cq]);
            fma_step(acc, pv.z, Ws[(4 * k4 + 2) * CQ + cq]);
            fma_step(acc, pv.w, Ws[(4 * k4 + 3) * CQ + cq]);
        }
        // add self-loop contribution and scale, then exchange agg quads via LDS
        {
            float4 pv = pr[cq];
            add4(agg, pv);
            agg.x *= inv; agg.y *= inv; agg.z *= inv; agg.w *= inv;
        }
        Ag[ns][cq] = agg;
        __syncthreads();
#pragma unroll 4
        for (int k4 = 0; k4 < KH / 4; ++k4) {
            float4 av = Ag[ns][k4];
            fma_step(acc, av.x, Ws[(KH + 4 * k4 + 0) * CQ + cq]);
            fma_step(acc, av.y, Ws[(KH + 4 * k4 + 1) * CQ + cq]);
            fma_step(acc, av.z, Ws[(KH + 4 * k4 + 2) * CQ + cq]);
            fma_step(acc, av.w, Ws[(KH + 4 * k4 + 3) * CQ + cq]);
        }
        __syncthreads();
        acc.x = fmaxf(acc.x, 0.0f);
        acc.y = fmaxf(acc.y, 0.0f);
        acc.z = fmaxf(acc.z, 0.0f);
        acc.w = fmaxf(acc.w, 0.0f);
        reinterpret_cast<float4*>(Y + (size_t)node * C)[cq] = acc;
    }
}

// ---------- conv2 update (gather) fused with final 32->1 linear ----------
__global__ void update2_final(const float* __restrict__ P,
                              const int* __restrict__ rowptr, const int* __restrict__ cnt,
                              const int* __restrict__ adj,
                              const float* __restrict__ W, const float* __restrict__ bias,
                              const float* __restrict__ Wl, const float* __restrict__ bl,
                              float* __restrict__ out, int n) {
    __shared__ float Ws[64 * 32];   // 8 KB
    for (int i = threadIdx.x; i < 64 * 32; i += BLK) Ws[i] = W[i];
    __syncthreads();
    const int c = threadIdx.x & 31;       // channel
    const int ns = threadIdx.x >> 5;      // 0..7 node slots
    const float wl = Wl[c];
    const float bc = bias[c];
    const float blv = bl[0];
    const int ntiles = (n + 7) / 8;       // divides evenly (100000 / 8)
    for (int tile = blockIdx.x; tile < ntiles; tile += gridDim.x) {
        const int node = tile * 8 + ns;
        const int start = rowptr[node];
        const int deg = cnt[node];
        const float inv = 1.0f / (float)(deg + 1);
        const float selfp = P[(size_t)node * 32 + c];
        float agg = 0.0f;
        int j = 0;
        for (; j + 1 < deg; j += 2) {
            const int s0 = adj[start + j];
            const int s1 = adj[start + j + 1];
            agg += P[(size_t)s0 * 32 + c] + P[(size_t)s1 * 32 + c];
        }
        if (j < deg) agg += P[(size_t)adj[start + j] * 32 + c];
        agg = (agg + selfp) * inv;

        // cooperative GEMM: lane c accumulates output channel c of its node.
        // width-32 shuffle broadcasts within each 32-lane node group.
        float acc = bc;
#pragma unroll
        for (int k = 0; k < 32; ++k) {
            float pk = __shfl(selfp, k, 32);
            float ak = __shfl(agg,   k, 32);
            acc = fmaf(pk, Ws[k * 32 + c], acc);
            acc = fmaf(ak, Ws[(32 + k) * 32 + c], acc);
        }
        float v = fmaxf(acc, 0.0f) * wl;
#pragma unroll
        for (int off = 16; off >= 1; off >>= 1) v += __shfl_xor(v, off, 32);
        if (c == 0) out[node] = v + blv;
    }
}

extern "C" void kernel_launch(void* const* d_in, const int* in_sizes, int n_in,
                              void* d_out, int out_size, void* d_ws, size_t ws_size,
                              hipStream_t stream) {
    const float* x    = (const float*)d_in[0];
    const int*   eraw = (const int*)d_in[1];
    const float* W2_1 = (const float*)d_in[2];
    const float* b2_1 = (const float*)d_in[3];
    const float* W1_1 = (const float*)d_in[4];
    const float* b1_1 = (const float*)d_in[5];
    const float* W2_2 = (const float*)d_in[6];
    const float* b2_2 = (const float*)d_in[7];
    const float* W1_2 = (const float*)d_in[8];
    const float* b1_2 = (const float*)d_in[9];
    const float* Wl   = (const float*)d_in[10];
    const float* bl   = (const float*)d_in[11];
    float* out = (float*)d_out;

    // workspace layout
    char* ws = (char*)d_ws;
    int* flag = (int*)ws;
    int* e32  = (int*)(ws + 256);                              // 12.8 MB
    size_t off = 256 + sizeof(int) * 2 * (size_t)N_EDGES;
    int* cnt    = (int*)(ws + off); off += sizeof(int) * (size_t)N_NODES;
    int* rowptr = (int*)(ws + off); off += sizeof(int) * (size_t)N_NODES;
    int* cursor = (int*)(ws + off); off += sizeof(int) * (size_t)N_NODES;
    int* bsum   = (int*)(ws + off); off += sizeof(int) * (size_t)(NB_SCAN + 8);
    off = (off + 255) & ~(size_t)255;
    int* adj    = (int*)(ws + off); off += sizeof(int) * (size_t)N_EDGES;   // 6.4 MB
    off = (off + 255) & ~(size_t)255;
    float* bufA = (float*)(ws + off); off += sizeof(float) * (size_t)N_NODES * 64;
    float* bufC = (float*)(ws + off); off += sizeof(float) * (size_t)N_NODES * 64;

    const int* src = e32;
    const int* dst = e32 + N_EDGES;

    hipMemsetAsync(cnt, 0, sizeof(int) * (size_t)N_NODES, stream);

    detect_idx64<<<1, 64, 0, stream>>>((const unsigned int*)eraw, flag);
    convert_edges<<<(2 * N_EDGES + BLK - 1) / BLK, BLK, 0, stream>>>(eraw, e32, 2 * N_EDGES, flag);
    degree_kernel<<<(N_EDGES + BLK - 1) / BLK, BLK, 0, stream>>>(dst, cnt);

    // CSR build
    scan_block<<<NB_SCAN, 256, 0, stream>>>(cnt, rowptr, bsum, N_NODES);
    scan_bsum<<<1, 256, 0, stream>>>(bsum, NB_SCAN);
    scan_add<<<NB_SCAN, 256, 0, stream>>>(rowptr, cursor, bsum, N_NODES);
    fill_csr<<<(N_EDGES + BLK - 1) / BLK, BLK, 0, stream>>>(src, dst, cursor, adj);

    // conv1
    gemm_bias<128, 64><<<2048, BLK, 0, stream>>>(x, W2_1, b2_1, bufA, N_NODES);
    update_gather<64, 64><<<2048, BLK, 0, stream>>>(bufA, rowptr, cnt, adj, W1_1, b1_1, bufC, N_NODES);

    // conv2
    gemm_bias<64, 32><<<2048, BLK, 0, stream>>>(bufC, W2_2, b2_2, bufA, N_NODES);
    update2_final<<<4096, BLK, 0, stream>>>(bufA, rowptr, cnt, adj, W1_2, b1_2, Wl, bl, out, N_NODES);
}